// Round 2
// baseline (467.720 us; speedup 1.0000x reference)
//
#include <hip/hip_runtime.h>

// B=4096 rows, N=16384 neurons, F=16384 features.
//
// Accounting (from rocprof): the timed region contains ~331 us of harness
// poison fills (2 x 1-GiB fillBuffer @ ~165 us); the kernel itself was
// ~102 us in round 0 vs an ~83 us HBM floor (537 MB at 6.5 TB/s).
//
// This version pipelines across rows to close that gap: each block owns
// RPB=8 consecutive rows. While gathering row r from LDS, row r+1 is parked
// in registers (T14 reg-staging) and row r+2's loads are issued. The
// stage->gather barrier is a raw lgkmcnt(0)+s_barrier (LDS hazard only) so
// in-flight HBM prefetch loads are NOT drained at the barrier. Mean is the
// round-0 gather-then-reduce path (absmax ~5e-4; the round-1 c-dot trick
// regressed accuracy and perf and is reverted). Nontemporal hints on the
// enc/out streams keep pref/w hot in L2.

typedef float f32x4 __attribute__((ext_vector_type(4)));

constexpr int B_ROWS  = 4096;
constexpr int N_NEUR  = 16384;
constexpr int F_FEAT  = 16384;
constexpr int THREADS = 512;
constexpr int WAVES   = THREADS / 64;          // 8
constexpr int RPB     = 8;                     // rows per block
constexpr int GRID    = B_ROWS / RPB;          // 512 blocks -> 2/CU, all resident
constexpr int VPT     = N_NEUR / THREADS;      // 32 gathered values per thread
constexpr int CH      = VPT / 4;               // 8 float4 chunks
constexpr int SCH     = F_FEAT / 4 / THREADS;  // 8 staging float4 chunks
constexpr float MEAN_SUB = 0.1f;

__global__ void __launch_bounds__(THREADS, 4)
sensory_pipe(const float* __restrict__ enc,
             const float* __restrict__ w,
             const int*   __restrict__ pref,
             float*       __restrict__ msum,   // [GRID*RPB*WAVES] scratch, write-once slots
             float*       __restrict__ out) {
  __shared__ float row[F_FEAT];                // 64 KB -> 2 blocks/CU
  f32x4* row4 = (f32x4*)row;

  const int tid  = threadIdx.x;
  const int b    = blockIdx.x;
  const int row0 = b * RPB;

  const int4*  __restrict__ pref4 = (const int4*)pref;
  const f32x4* __restrict__ wv4   = (const f32x4*)w;

  // ---- prologue: row0 -> regs -> LDS; prefetch row1 into regs ----
  f32x4 e[SCH];
  {
    const f32x4* eg0 = (const f32x4*)(enc + (size_t)row0 * F_FEAT);
    #pragma unroll
    for (int j = 0; j < SCH; ++j)
      e[j] = __builtin_nontemporal_load(&eg0[tid + j * THREADS]);
    #pragma unroll
    for (int j = 0; j < SCH; ++j)
      row4[tid + j * THREADS] = e[j];
    const f32x4* eg1 = (const f32x4*)(enc + (size_t)(row0 + 1) * F_FEAT);
    #pragma unroll
    for (int j = 0; j < SCH; ++j)
      e[j] = __builtin_nontemporal_load(&eg1[tid + j * THREADS]);
  }
  __syncthreads();

  for (int r = 0; r < RPB; ++r) {
    // ---- gather row r from LDS, keep in regs, accumulate local sum ----
    float v[VPT];
    float lsum = 0.0f;
    #pragma unroll
    for (int k = 0; k < CH; ++k) {
      const int n4 = k * THREADS + tid;        // float4/int4 index
      const int4  p4 = pref4[n4];
      const f32x4 w4 = wv4[n4];
      const float a0 = row[p4.x & (F_FEAT - 1)] * w4.x;
      const float a1 = row[p4.y & (F_FEAT - 1)] * w4.y;
      const float a2 = row[p4.z & (F_FEAT - 1)] * w4.z;
      const float a3 = row[p4.w & (F_FEAT - 1)] * w4.w;
      v[k * 4 + 0] = a0;
      v[k * 4 + 1] = a1;
      v[k * 4 + 2] = a2;
      v[k * 4 + 3] = a3;
      lsum += (a0 + a1) + (a2 + a3);
    }

    // ---- wave reduce; partials to a write-once global slot ----
    #pragma unroll
    for (int off = 32; off > 0; off >>= 1)
      lsum += __shfl_down(lsum, off, 64);
    const size_t slot = (size_t)(b * RPB + r) * WAVES;
    if ((tid & 63) == 0) msum[slot + (tid >> 6)] = lsum;

    __syncthreads();   // full drain: gathers done, partials visible (L1 write-through)

    const f32x4 s0 = *(const f32x4*)(msum + slot);
    const f32x4 s1 = *(const f32x4*)(msum + slot + 4);
    const float sub = (((s0.x + s0.y) + (s0.z + s0.w)) +
                       ((s1.x + s1.y) + (s1.z + s1.w))) * (MEAN_SUB / (float)N_NEUR);

    // ---- subtract, rectify, nontemporal store of row r ----
    float* outrow = out + (size_t)(row0 + r) * N_NEUR;
    #pragma unroll
    for (int k = 0; k < CH; ++k) {
      const int n = k * (THREADS * 4) + tid * 4;
      f32x4 o;
      o.x = fmaxf(v[k * 4 + 0] - sub, 0.0f);
      o.y = fmaxf(v[k * 4 + 1] - sub, 0.0f);
      o.z = fmaxf(v[k * 4 + 2] - sub, 0.0f);
      o.w = fmaxf(v[k * 4 + 3] - sub, 0.0f);
      __builtin_nontemporal_store(o, (f32x4*)(outrow + n));
    }

    // ---- stage row r+1 (regs->LDS), issue prefetch of row r+2 ----
    if (r < RPB - 1) {
      #pragma unroll
      for (int j = 0; j < SCH; ++j)
        row4[tid + j * THREADS] = e[j];
      if (r < RPB - 2) {
        const f32x4* egn = (const f32x4*)(enc + (size_t)(row0 + r + 2) * F_FEAT);
        #pragma unroll
        for (int j = 0; j < SCH; ++j)
          e[j] = __builtin_nontemporal_load(&egn[tid + j * THREADS]);
      }
      // LDS-only barrier: wait own ds_writes, sync, but do NOT drain the
      // in-flight row r+2 global loads (that is the point of the pipeline).
      asm volatile("s_waitcnt lgkmcnt(0)" ::: "memory");
      __builtin_amdgcn_s_barrier();
      asm volatile("" ::: "memory");
    }
  }
}

extern "C" void kernel_launch(void* const* d_in, const int* in_sizes, int n_in,
                              void* d_out, int out_size, void* d_ws, size_t ws_size,
                              hipStream_t stream) {
  const float* enc  = (const float*)d_in[0];   // [B, F] f32
  const float* w    = (const float*)d_in[1];   // [N] f32
  const int*   pref = (const int*)d_in[2];     // [N] i32
  float*       out  = (float*)d_out;           // [B, N] f32
  float*       msum = (float*)d_ws;            // 512*8*8 floats = 128 KB

  sensory_pipe<<<GRID, THREADS, 0, stream>>>(enc, w, pref, msum, out);
}

// Round 3
// 435.582 us; speedup vs baseline: 1.0738x; 1.0738x over previous
//
#include <hip/hip_runtime.h>

// B=4096 rows, N=16384 neurons, F=16384 features.
//
// Accounting (rocprof): timed region = ~331 us of harness poison fills
// (2 x 1-GiB fillBuffer @ ~165 us, 6.5 TB/s) + this kernel. Kernel HBM
// floor = (268 MB enc read + 268 MB out write) / 6.29 TB/s ~= 85 us.
// Round-0 structure (one row per block, 4096 blocks, 16 queued/CU) was
// ~102 us; rounds 1-2 proved block-level TLP beats in-block pipelining
// (both regressed). This version is round 0 with ONLY the reduction
// streamlined:
//   - partials go to a dedicated red[8] LDS array (not reused row[]),
//     removing the pre-partial barrier;
//   - every thread sums the 8 partials via broadcast LDS reads,
//     removing the serial tid==0 tail and its two barriers.
// Net: 4 barriers + serial tail -> 2 barriers, zero other changes.

constexpr int B_ROWS  = 4096;
constexpr int N_NEUR  = 16384;
constexpr int F_FEAT  = 16384;
constexpr int THREADS = 512;
constexpr int WAVES   = THREADS / 64;          // 8
constexpr int VPT     = N_NEUR / THREADS;      // 32 values per thread
constexpr int CH      = VPT / 4;               // 8 float4 chunks
constexpr int SCH     = F_FEAT / 4 / THREADS;  // 8 staging float4 chunks
constexpr float MEAN_SUB = 0.1f;

__global__ void __launch_bounds__(THREADS, 4)
sensory_kernel(const float* __restrict__ enc,
               const float* __restrict__ w,
               const int*   __restrict__ pref,
               float*       __restrict__ out) {
    __shared__ float row[F_FEAT];   // 64 KB -> 2 blocks/CU (LDS-capped)
    __shared__ float red[WAVES];    // 32 B, dedicated reduction slots

    const int tid = threadIdx.x;
    const int b   = blockIdx.x;

    // ---- stage encoded_features[b, :] into LDS (coalesced float4) ----
    const float4* __restrict__ rowg4 = (const float4*)(enc + (size_t)b * F_FEAT);
    float4* row4 = (float4*)row;
    #pragma unroll
    for (int j = 0; j < SCH; ++j)
        row4[tid + j * THREADS] = rowg4[tid + j * THREADS];
    __syncthreads();

    // ---- gather * weight, keep in registers, accumulate local sum ----
    float v[VPT];
    float lsum = 0.0f;
    const int4*   __restrict__ pref4 = (const int4*)pref;
    const float4* __restrict__ wv4   = (const float4*)w;
    #pragma unroll
    for (int k = 0; k < CH; ++k) {
        const int n4 = k * THREADS + tid;       // int4/float4 index
        const int4   p4 = pref4[n4];
        const float4 w4 = wv4[n4];
        const float a0 = row[p4.x & (F_FEAT - 1)] * w4.x;
        const float a1 = row[p4.y & (F_FEAT - 1)] * w4.y;
        const float a2 = row[p4.z & (F_FEAT - 1)] * w4.z;
        const float a3 = row[p4.w & (F_FEAT - 1)] * w4.w;
        v[k * 4 + 0] = a0;
        v[k * 4 + 1] = a1;
        v[k * 4 + 2] = a2;
        v[k * 4 + 3] = a3;
        lsum += (a0 + a1) + (a2 + a3);
    }

    // ---- wave shuffle reduce; one barrier; broadcast final sum ----
    #pragma unroll
    for (int off = 32; off > 0; off >>= 1)
        lsum += __shfl_down(lsum, off, 64);
    if ((tid & 63) == 0) red[tid >> 6] = lsum;
    __syncthreads();

    float t = 0.0f;
    #pragma unroll
    for (int i = 0; i < WAVES; ++i) t += red[i];   // broadcast reads, all lanes
    const float sub = t * (MEAN_SUB / (float)N_NEUR);

    // ---- subtract, rectify, coalesced float4 store ----
    float* __restrict__ outrow = out + (size_t)b * N_NEUR;
    #pragma unroll
    for (int k = 0; k < CH; ++k) {
        const int n = k * (THREADS * 4) + tid * 4;
        float4 o;
        o.x = fmaxf(v[k * 4 + 0] - sub, 0.0f);
        o.y = fmaxf(v[k * 4 + 1] - sub, 0.0f);
        o.z = fmaxf(v[k * 4 + 2] - sub, 0.0f);
        o.w = fmaxf(v[k * 4 + 3] - sub, 0.0f);
        *(float4*)(outrow + n) = o;
    }
}

extern "C" void kernel_launch(void* const* d_in, const int* in_sizes, int n_in,
                              void* d_out, int out_size, void* d_ws, size_t ws_size,
                              hipStream_t stream) {
    const float* enc  = (const float*)d_in[0];   // [B, F] f32
    const float* w    = (const float*)d_in[1];   // [N] f32
    const int*   pref = (const int*)d_in[2];     // [N] i32
    float*       out  = (float*)d_out;           // [B, N] f32
    sensory_kernel<<<B_ROWS, THREADS, 0, stream>>>(enc, w, pref, out);
}

// Round 5
// 432.445 us; speedup vs baseline: 1.0816x; 1.0073x over previous
//
#include <hip/hip_runtime.h>

// B=4096 rows, N=16384 neurons, F=16384 features.
//
// Accounting (rocprof, rounds 0-3): timed region = ~331 us of harness poison
// fills (2 x 1-GiB fillBuffer @ ~165 us) + kernel. Kernel HBM floor =
// (268 MB enc read + 268 MB out write) / 6.29 TB/s ~= 85 us. Round-0
// structure = ~102 us. R1 (c-dot mean) and R2 (in-block pipeline) regressed;
// R3 (fewer barriers) was neutral. R4 (this experiment + global_load_lds)
// died to a container failure; retrying WITHOUT global_load_lds to isolate
// the single variable and remove the only unproven ingredient.
//
// Experiment: OCCUPANCY. 64 KB LDS caps at 2 blocks/CU; at 512 threads that
// is 16 waves/CU (50%). 1024-thread blocks keep 2 blocks/CU but give
// 32 waves/CU (100%), doubling the latency-hiding pool for the HBM stream
// that the gather phase must overlap. __launch_bounds__(1024,8) pins
// VGPR <= 64 so both blocks stay resident (live set ~50 regs: v[16] +
// staging/gather temps). Macro-structure otherwise identical to round 3.

constexpr int B_ROWS  = 4096;
constexpr int N_NEUR  = 16384;
constexpr int F_FEAT  = 16384;
constexpr int THREADS = 1024;
constexpr int WAVES   = THREADS / 64;          // 16
constexpr int VPT     = N_NEUR / THREADS;      // 16 values per thread
constexpr int CH      = VPT / 4;               // 4 float4 chunks
constexpr int SCH     = F_FEAT / 4 / THREADS;  // 4 staging float4 chunks
constexpr float MEAN_SUB = 0.1f;

__global__ void __launch_bounds__(THREADS, 8)
sensory_kernel(const float* __restrict__ enc,
               const float* __restrict__ w,
               const int*   __restrict__ pref,
               float*       __restrict__ out) {
    __shared__ float row[F_FEAT];   // 64 KB -> 2 blocks/CU (LDS-capped)
    __shared__ float red[WAVES];    // dedicated reduction slots

    const int tid = threadIdx.x;
    const int b   = blockIdx.x;

    // ---- stage encoded_features[b, :] into LDS (coalesced float4) ----
    const float4* __restrict__ rowg4 = (const float4*)(enc + (size_t)b * F_FEAT);
    float4* row4 = (float4*)row;
    #pragma unroll
    for (int j = 0; j < SCH; ++j) {
        const int i = tid + j * THREADS;
        row4[i] = rowg4[i];
    }
    __syncthreads();

    // ---- gather * weight, keep in registers, accumulate local sum ----
    float v[VPT];
    float lsum = 0.0f;
    const int4*   __restrict__ pref4 = (const int4*)pref;
    const float4* __restrict__ wv4   = (const float4*)w;
    #pragma unroll
    for (int k = 0; k < CH; ++k) {
        const int n4 = k * THREADS + tid;       // int4/float4 index
        const int4   p4 = pref4[n4];
        const float4 w4 = wv4[n4];
        const float a0 = row[p4.x & (F_FEAT - 1)] * w4.x;
        const float a1 = row[p4.y & (F_FEAT - 1)] * w4.y;
        const float a2 = row[p4.z & (F_FEAT - 1)] * w4.z;
        const float a3 = row[p4.w & (F_FEAT - 1)] * w4.w;
        v[k * 4 + 0] = a0;
        v[k * 4 + 1] = a1;
        v[k * 4 + 2] = a2;
        v[k * 4 + 3] = a3;
        lsum += (a0 + a1) + (a2 + a3);
    }

    // ---- wave shuffle reduce; one barrier; broadcast final sum ----
    #pragma unroll
    for (int off = 32; off > 0; off >>= 1)
        lsum += __shfl_down(lsum, off, 64);
    if ((tid & 63) == 0) red[tid >> 6] = lsum;
    __syncthreads();

    float t = 0.0f;
    #pragma unroll
    for (int i = 0; i < WAVES; ++i) t += red[i];   // broadcast reads
    const float sub = t * (MEAN_SUB / (float)N_NEUR);

    // ---- subtract, rectify, coalesced float4 store ----
    float* __restrict__ outrow = out + (size_t)b * N_NEUR;
    #pragma unroll
    for (int k = 0; k < CH; ++k) {
        const int n = k * (THREADS * 4) + tid * 4;
        float4 o;
        o.x = fmaxf(v[k * 4 + 0] - sub, 0.0f);
        o.y = fmaxf(v[k * 4 + 1] - sub, 0.0f);
        o.z = fmaxf(v[k * 4 + 2] - sub, 0.0f);
        o.w = fmaxf(v[k * 4 + 3] - sub, 0.0f);
        *(float4*)(outrow + n) = o;
    }
}

extern "C" void kernel_launch(void* const* d_in, const int* in_sizes, int n_in,
                              void* d_out, int out_size, void* d_ws, size_t ws_size,
                              hipStream_t stream) {
    const float* enc  = (const float*)d_in[0];   // [B, F] f32
    const float* w    = (const float*)d_in[1];   // [N] f32
    const int*   pref = (const int*)d_in[2];     // [N] i32
    float*       out  = (float*)d_out;           // [B, N] f32
    sensory_kernel<<<B_ROWS, THREADS, 0, stream>>>(enc, w, pref, out);
}